// Round 8
// baseline (116.891 us; speedup 1.0000x reference)
//
#include <hip/hip_runtime.h>

// Problem: SpatialTransform
//   x: (16,256,256,32) f32 -> out: (16,256,256,32) f32
//   theta = mean_pool(x) @ W_loc + b_loc;  out = bilinear_sample(x, affine_grid(theta))
//
// R7 lesson: theta-dependent bbox staging was latency-serialized (runtime
// bounds -> row-by-row load+wait+write). R8: FIXED conservative stage region
// (theta ~ identity +-0.9px, checked; fallback to direct gather), loads issued
// before the theta preamble into registers, batch ds_write, unrolled blend.

#define NIMG 16
#define HDIM 256
#define WDIM 256
#define CH   32
#define HW   (HDIM * WDIM)
#define BPI  64        // sum-kernel blocks per image

#define R_CAP 10                 // staged rows   (tile 8 + 1 halo each side)
#define C_CAP 36                 // staged cols   (tile 32 + 2 halo each side)
#define C8    (C_CAP * 8)        // float4 per staged row = 288
#define STAGE_N (R_CAP * C8)     // 2880 float4 = 45 KB
#define NLD   12                 // ceil(2880/256) register-buffered loads

typedef float f32x4 __attribute__((ext_vector_type(4)));

// ---------------------------------------------------------------------------
// Kernel 1: per-(n,c) partial sums. 1024 blocks, 4 independent acc chains.
// partials layout: [BPI][NIMG][CH]
// ---------------------------------------------------------------------------
__global__ __launch_bounds__(256) void st_sum_kernel(
    const float* __restrict__ x, float* __restrict__ partials) {
    const int n   = blockIdx.x >> 6;
    const int blk = blockIdx.x & (BPI - 1);
    const int tid = threadIdx.x;
    const int cg  = tid & 7;
    const int sp  = tid >> 3;

    const float4* xp = (const float4*)(x + (size_t)n * HW * CH);
    float4 a0 = make_float4(0.f, 0.f, 0.f, 0.f);
    float4 a1 = make_float4(0.f, 0.f, 0.f, 0.f);
    float4 a2 = make_float4(0.f, 0.f, 0.f, 0.f);
    float4 a3 = make_float4(0.f, 0.f, 0.f, 0.f);
    int s = blk * 32 + sp;   // slot stride: BPI*32 = 2048
    #pragma unroll
    for (int it = 0; it < 8; ++it) {
        float4 v0 = xp[(size_t)(s       ) * 8 + cg];
        float4 v1 = xp[(size_t)(s + 2048) * 8 + cg];
        float4 v2 = xp[(size_t)(s + 4096) * 8 + cg];
        float4 v3 = xp[(size_t)(s + 6144) * 8 + cg];
        a0.x += v0.x; a0.y += v0.y; a0.z += v0.z; a0.w += v0.w;
        a1.x += v1.x; a1.y += v1.y; a1.z += v1.z; a1.w += v1.w;
        a2.x += v2.x; a2.y += v2.y; a2.z += v2.z; a2.w += v2.w;
        a3.x += v3.x; a3.y += v3.y; a3.z += v3.z; a3.w += v3.w;
        s += 8192;
    }
    a0.x += a1.x; a0.y += a1.y; a0.z += a1.z; a0.w += a1.w;
    a2.x += a3.x; a2.y += a3.y; a2.z += a3.z; a2.w += a3.w;
    a0.x += a2.x; a0.y += a2.y; a0.z += a2.z; a0.w += a2.w;

    __shared__ float4 red[256];
    red[tid] = a0;
    __syncthreads();
    for (int stride = 16; stride >= 1; stride >>= 1) {
        if (sp < stride) {
            float4 o = red[(sp + stride) * 8 + cg];
            a0.x += o.x; a0.y += o.y; a0.z += o.z; a0.w += o.w;
            red[tid] = a0;
        }
        __syncthreads();
    }
    if (sp == 0) {
        ((float4*)(partials + ((size_t)blk * NIMG + n) * CH))[cg] = a0;
    }
}

// ---------------------------------------------------------------------------
// Kernel 2: theta recompute + fixed-region LDS-staged bilinear gather.
// One block = 8x32 pixel tile (one px per thread, 8 row-iterations).
// 4096 blocks; XCD swizzle: 512 consecutive blocks (=2 images) per XCD.
// ---------------------------------------------------------------------------
__global__ __launch_bounds__(256) void st_interp_kernel(
    const float* __restrict__ x, const float* __restrict__ partials,
    const float* __restrict__ W_loc, const float* __restrict__ b_loc,
    float* __restrict__ out) {
    const int bid = (int)blockIdx.x;
    const int swz = (bid & 7) * 512 + (bid >> 3);  // 8 XCDs contiguous
    const int n   = swz >> 8;                      // 256 blocks per image
    const int r   = swz & 255;
    const int tid = threadIdx.x;

    const int ty = r >> 3, tx = r & 7;             // 32 tile-rows x 8 tile-cols
    const int row0 = ty * 8, col0 = tx * 32;

    __shared__ float  red2[8][CH];
    __shared__ float  th_s[8];
    __shared__ float4 stage[STAGE_N];              // 45 KB

    const float4* xp = (const float4*)(x + (size_t)n * HW * CH);

    // ---- (1) issue ALL staging loads (theta-independent addresses) ----
    float4 buf[NLD];
    #pragma unroll
    for (int i = 0; i < NLD; ++i) {
        const int u = tid + i * 256;
        if (u < STAGE_N) {
            const int rr  = u / C8;                // const-div (magic mul)
            const int m   = u - rr * C8;
            const int lx  = m >> 3, c2 = m & 7;
            const int sy  = min(max(row0 - 1 + rr, 0), HDIM - 1);
            const int sx  = min(max(col0 - 2 + lx, 0), WDIM - 1);
            buf[i] = xp[(size_t)(sy * WDIM + sx) * 8 + c2];
        }
    }

    // ---- (2) theta from partials (hides staging-load latency) ----
    {
        const int c = tid & 31, g = tid >> 5;
        float s = 0.f;
        #pragma unroll
        for (int j = 0; j < 8; ++j)
            s += partials[(size_t)((g * 8 + j) * NIMG + n) * CH + c];
        red2[g][c] = s;
        __syncthreads();
        if (g == 0) {
            float m = 0.f;
            #pragma unroll
            for (int j = 0; j < 8; ++j) m += red2[j][c];
            red2[0][c] = m * (1.0f / (float)HW);
        }
        __syncthreads();
        if (tid < 6) {
            float acc = b_loc[tid];
            for (int c2 = 0; c2 < CH; ++c2)
                acc = fmaf(red2[0][c2], W_loc[c2 * 6 + tid], acc);
            th_s[tid] = acc;
        }
        __syncthreads();
    }
    const float t00 = th_s[0], t01 = th_s[1], t02 = th_s[2];
    const float t10 = th_s[3], t11 = th_s[4], t12 = th_s[5];

    // ---- (3) conservative-region check (block-uniform; affine -> corners) ----
    const float gyA = fmaf((float)row0,        2.0f / 255.0f, -1.0f);
    const float gyB = fmaf((float)(row0 + 7),  2.0f / 255.0f, -1.0f);
    const float gxA = fmaf((float)col0,        2.0f / 255.0f, -1.0f);
    const float gxB = fmaf((float)(col0 + 31), 2.0f / 255.0f, -1.0f);
    const float uy1 = (fmaf(t00, gyA, fmaf(t01, gxA, t02)) + 1.0f) * 127.5f;
    const float uy2 = (fmaf(t00, gyA, fmaf(t01, gxB, t02)) + 1.0f) * 127.5f;
    const float uy3 = (fmaf(t00, gyB, fmaf(t01, gxA, t02)) + 1.0f) * 127.5f;
    const float uy4 = (fmaf(t00, gyB, fmaf(t01, gxB, t02)) + 1.0f) * 127.5f;
    const float ux1 = (fmaf(t10, gyA, fmaf(t11, gxA, t12)) + 1.0f) * 127.5f;
    const float ux2 = (fmaf(t10, gyA, fmaf(t11, gxB, t12)) + 1.0f) * 127.5f;
    const float ux3 = (fmaf(t10, gyB, fmaf(t11, gxB, t12)) + 1.0f) * 127.5f;
    const float ux4 = (fmaf(t10, gyB, fmaf(t11, gxA, t12)) + 1.0f) * 127.5f;
    const float uymin = fminf(fminf(uy1, uy2), fminf(uy3, uy4));
    const float uymax = fmaxf(fmaxf(uy1, uy2), fmaxf(uy3, uy4));
    const float uxmin = fminf(fminf(ux1, ux2), fminf(ux3, ux4));
    const float uxmax = fmaxf(fmaxf(ux1, ux2), fmaxf(ux3, ux4));
    // positive conjunction: NaN anywhere -> false -> fallback
    const bool fits = (uymin > (float)row0 - 0.9f) && (uymax < (float)row0 + 7.9f) &&
                      (uxmin > (float)col0 - 1.9f) && (uxmax < (float)col0 + 32.9f);

    const int p  = tid >> 3;       // column within tile 0..31
    const int cg = tid & 7;        // float4 channel group
    const int wo = col0 + p;
    const float gx  = fmaf((float)wo, 2.0f / 255.0f, -1.0f);
    const float ayx = fmaf(t01, gx, t02);  // uy = t00*gy + ayx
    const float axx = fmaf(t11, gx, t12);  // ux = t10*gy + axx

    f32x4* op = (f32x4*)(out + (size_t)n * HW * CH);

    if (fits) {
        // ---- (4) batch ds_write, sync, unrolled blend from LDS ----
        #pragma unroll
        for (int i = 0; i < NLD; ++i) {
            const int u = tid + i * 256;
            if (u < STAGE_N) stage[u] = buf[i];
        }
        __syncthreads();

        const int iy_lo = row0 - 1, ix_lo = col0 - 2;
        #pragma unroll
        for (int k = 0; k < 8; ++k) {
            const int ho = row0 + k;
            const float gy = fmaf((float)ho, 2.0f / 255.0f, -1.0f);
            const float uy = (fmaf(t00, gy, ayx) + 1.0f) * 127.5f;
            const float ux = (fmaf(t10, gy, axx) + 1.0f) * 127.5f;
            const float fy = floorf(uy), fx = floorf(ux);
            const float ry = uy - fy, rx = ux - fx;
            const int iy0 = min(max((int)fy,     0), HDIM - 1);
            const int iy1 = min(max((int)fy + 1, 0), HDIM - 1);
            const int ix0 = min(max((int)fx,     0), WDIM - 1);
            const int ix1 = min(max((int)fx + 1, 0), WDIM - 1);
            const int ly0 = iy0 - iy_lo, ly1 = iy1 - iy_lo;
            const int lx0 = ix0 - ix_lo, lx1 = ix1 - ix_lo;
            float4 v00 = stage[(ly0 * C_CAP + lx0) * 8 + cg];
            float4 v01 = stage[(ly0 * C_CAP + lx1) * 8 + cg];
            float4 v10 = stage[(ly1 * C_CAP + lx0) * 8 + cg];
            float4 v11 = stage[(ly1 * C_CAP + lx1) * 8 + cg];
            const float w00 = (1.0f - ry) * (1.0f - rx);
            const float w01 = (1.0f - ry) * rx;
            const float w10 = ry * (1.0f - rx);
            const float w11 = ry * rx;
            f32x4 o;
            o.x = v00.x * w00 + v01.x * w01 + v10.x * w10 + v11.x * w11;
            o.y = v00.y * w00 + v01.y * w01 + v10.y * w10 + v11.y * w11;
            o.z = v00.z * w00 + v01.z * w01 + v10.z * w10 + v11.z * w11;
            o.w = v00.w * w00 + v01.w * w01 + v10.w * w10 + v11.w * w11;
            __builtin_nontemporal_store(o, &op[(size_t)(ho * WDIM + wo) * 8 + cg]);
        }
    } else {
        // ---- fallback: direct gather (correct for arbitrary theta) ----
        for (int k = 0; k < 8; ++k) {
            const int ho = row0 + k;
            const float gy = fmaf((float)ho, 2.0f / 255.0f, -1.0f);
            const float uy = (fmaf(t00, gy, ayx) + 1.0f) * 127.5f;
            const float ux = (fmaf(t10, gy, axx) + 1.0f) * 127.5f;
            const float fy = floorf(uy), fx = floorf(ux);
            const float ry = uy - fy, rx = ux - fx;
            const int iy0 = min(max((int)fy,     0), HDIM - 1);
            const int iy1 = min(max((int)fy + 1, 0), HDIM - 1);
            const int ix0 = min(max((int)fx,     0), WDIM - 1);
            const int ix1 = min(max((int)fx + 1, 0), WDIM - 1);
            float4 v00 = xp[(size_t)(iy0 * WDIM + ix0) * 8 + cg];
            float4 v01 = xp[(size_t)(iy0 * WDIM + ix1) * 8 + cg];
            float4 v10 = xp[(size_t)(iy1 * WDIM + ix0) * 8 + cg];
            float4 v11 = xp[(size_t)(iy1 * WDIM + ix1) * 8 + cg];
            const float w00 = (1.0f - ry) * (1.0f - rx);
            const float w01 = (1.0f - ry) * rx;
            const float w10 = ry * (1.0f - rx);
            const float w11 = ry * rx;
            f32x4 o;
            o.x = v00.x * w00 + v01.x * w01 + v10.x * w10 + v11.x * w11;
            o.y = v00.y * w00 + v01.y * w01 + v10.y * w10 + v11.y * w11;
            o.z = v00.z * w00 + v01.z * w01 + v10.z * w10 + v11.z * w11;
            o.w = v00.w * w00 + v01.w * w01 + v10.w * w10 + v11.w * w11;
            __builtin_nontemporal_store(o, &op[(size_t)(ho * WDIM + wo) * 8 + cg]);
        }
    }
}

extern "C" void kernel_launch(void* const* d_in, const int* in_sizes, int n_in,
                              void* d_out, int out_size, void* d_ws, size_t ws_size,
                              hipStream_t stream) {
    const float* x     = (const float*)d_in[0];
    const float* W_loc = (const float*)d_in[1];
    const float* b_loc = (const float*)d_in[2];
    float* out = (float*)d_out;

    float* partials = (float*)d_ws;  // [BPI][NIMG][CH]

    st_sum_kernel<<<NIMG * BPI, 256, 0, stream>>>(x, partials);
    st_interp_kernel<<<NIMG * (HW / 256), 256, 0, stream>>>(
        x, partials, W_loc, b_loc, out);
}

// Round 9
// 65.512 us; speedup vs baseline: 1.7843x; 1.7843x over previous
//
#include <hip/hip_runtime.h>

// Problem: SpatialTransform
//   x: (16,256,256,32) f32 -> out: (16,256,256,32) f32
//   theta = mean_pool(x) @ W_loc + b_loc;  out = bilinear_sample(x, affine_grid(theta))
//
// R8 lesson: register-buffered staging spilled to scratch (WRITE 315MB, VGPR 68).
// R9: stage via global_load_lds -- per-lane CLAMPED global src, linear LDS dest,
// no VGPR round-trip. DMA issued before theta preamble; preamble's first
// __syncthreads (vmcnt(0) drain) completes it. Fallback: direct gather.

#define NIMG 16
#define HDIM 256
#define WDIM 256
#define CH   32
#define HW   (HDIM * WDIM)
#define BPI  64        // sum-kernel blocks per image

#define R_CAP 10                 // staged rows: [row0-1, row0+9)
#define C_CAP 36                 // staged cols: [col0-2, col0+34)
#define SLOT_ROW (C_CAP * 8)     // float4 slots per row = 288
#define SLOTS (R_CAP * SLOT_ROW) // 2880 float4 = 45 KB

typedef float f32x4 __attribute__((ext_vector_type(4)));

// ---------------------------------------------------------------------------
// Kernel 1: per-(n,c) partial sums. 1024 blocks, 4 independent acc chains.
// partials layout: [BPI][NIMG][CH]
// ---------------------------------------------------------------------------
__global__ __launch_bounds__(256) void st_sum_kernel(
    const float* __restrict__ x, float* __restrict__ partials) {
    const int n   = blockIdx.x >> 6;
    const int blk = blockIdx.x & (BPI - 1);
    const int tid = threadIdx.x;
    const int cg  = tid & 7;
    const int sp  = tid >> 3;

    const float4* xp = (const float4*)(x + (size_t)n * HW * CH);
    float4 a0 = make_float4(0.f, 0.f, 0.f, 0.f);
    float4 a1 = make_float4(0.f, 0.f, 0.f, 0.f);
    float4 a2 = make_float4(0.f, 0.f, 0.f, 0.f);
    float4 a3 = make_float4(0.f, 0.f, 0.f, 0.f);
    int s = blk * 32 + sp;   // slot stride: BPI*32 = 2048
    #pragma unroll
    for (int it = 0; it < 8; ++it) {
        float4 v0 = xp[(size_t)(s       ) * 8 + cg];
        float4 v1 = xp[(size_t)(s + 2048) * 8 + cg];
        float4 v2 = xp[(size_t)(s + 4096) * 8 + cg];
        float4 v3 = xp[(size_t)(s + 6144) * 8 + cg];
        a0.x += v0.x; a0.y += v0.y; a0.z += v0.z; a0.w += v0.w;
        a1.x += v1.x; a1.y += v1.y; a1.z += v1.z; a1.w += v1.w;
        a2.x += v2.x; a2.y += v2.y; a2.z += v2.z; a2.w += v2.w;
        a3.x += v3.x; a3.y += v3.y; a3.z += v3.z; a3.w += v3.w;
        s += 8192;
    }
    a0.x += a1.x; a0.y += a1.y; a0.z += a1.z; a0.w += a1.w;
    a2.x += a3.x; a2.y += a3.y; a2.z += a3.z; a2.w += a3.w;
    a0.x += a2.x; a0.y += a2.y; a0.z += a2.z; a0.w += a2.w;

    __shared__ float4 red[256];
    red[tid] = a0;
    __syncthreads();
    for (int stride = 16; stride >= 1; stride >>= 1) {
        if (sp < stride) {
            float4 o = red[(sp + stride) * 8 + cg];
            a0.x += o.x; a0.y += o.y; a0.z += o.z; a0.w += o.w;
            red[tid] = a0;
        }
        __syncthreads();
    }
    if (sp == 0) {
        ((float4*)(partials + ((size_t)blk * NIMG + n) * CH))[cg] = a0;
    }
}

// ---------------------------------------------------------------------------
// Kernel 2: theta recompute + global_load_lds-staged bilinear gather.
// One block = 8x32 pixel tile. 4096 blocks; XCD swizzle: 512 consecutive
// blocks (=2 images) per XCD. LDS stage holds rows [row0-1,row0+9) x cols
// [col0-2,col0+34), per-lane clamped; clamp-garbage halo slots never read.
// ---------------------------------------------------------------------------
__global__ __launch_bounds__(256) void st_interp_kernel(
    const float* __restrict__ x, const float* __restrict__ partials,
    const float* __restrict__ W_loc, const float* __restrict__ b_loc,
    float* __restrict__ out) {
    const int bid = (int)blockIdx.x;
    const int swz = (bid & 7) * 512 + (bid >> 3);  // 8 XCDs contiguous
    const int n   = swz >> 8;                      // 256 blocks per image
    const int r   = swz & 255;
    const int tid = threadIdx.x;

    const int ty = r >> 3, tx = r & 7;             // 32 tile-rows x 8 tile-cols
    const int row0 = ty * 8, col0 = tx * 32;

    __shared__ float  red2[8][CH];
    __shared__ float  th_s[8];
    __shared__ float4 stage[SLOTS];                // 45 KB

    const float4* xp = (const float4*)(x + (size_t)n * HW * CH);

    // ---- (1) issue staging DMA: per-lane clamped global src, linear LDS ----
    #pragma unroll
    for (int i = 0; i < 12; ++i) {
        const int u = tid + i * 256;
        if (i < 11 || tid < 64) {                  // u < SLOTS (wave-uniform)
            const int rr = u / SLOT_ROW;           // const-div
            const int m  = u - rr * SLOT_ROW;
            const int lx = m >> 3, c2 = m & 7;
            const int sy = min(max(row0 - 1 + rr, 0), HDIM - 1);
            const int sx = min(max(col0 - 2 + lx, 0), WDIM - 1);
            const float4* gp = xp + (size_t)(sy * WDIM + sx) * 8 + c2;
            __builtin_amdgcn_global_load_lds(
                (const __attribute__((address_space(1))) void*)gp,
                (__attribute__((address_space(3))) void*)&stage[u], 16, 0, 0);
        }
    }

    // ---- (2) theta from partials (first barrier also drains the DMA) ----
    {
        const int c = tid & 31, g = tid >> 5;
        float s = 0.f;
        #pragma unroll
        for (int j = 0; j < 8; ++j)
            s += partials[(size_t)((g * 8 + j) * NIMG + n) * CH + c];
        red2[g][c] = s;
        __syncthreads();
        if (g == 0) {
            float m = 0.f;
            #pragma unroll
            for (int j = 0; j < 8; ++j) m += red2[j][c];
            red2[0][c] = m * (1.0f / (float)HW);
        }
        __syncthreads();
        if (tid < 6) {
            float acc = b_loc[tid];
            for (int c2 = 0; c2 < CH; ++c2)
                acc = fmaf(red2[0][c2], W_loc[c2 * 6 + tid], acc);
            th_s[tid] = acc;
        }
        __syncthreads();
    }
    const float t00 = th_s[0], t01 = th_s[1], t02 = th_s[2];
    const float t10 = th_s[3], t11 = th_s[4], t12 = th_s[5];

    // ---- (3) conservative-region check (block-uniform, NaN-safe) ----
    const float gyA = fmaf((float)row0,        2.0f / 255.0f, -1.0f);
    const float gyB = fmaf((float)(row0 + 7),  2.0f / 255.0f, -1.0f);
    const float gxA = fmaf((float)col0,        2.0f / 255.0f, -1.0f);
    const float gxB = fmaf((float)(col0 + 31), 2.0f / 255.0f, -1.0f);
    const float uy1 = (fmaf(t00, gyA, fmaf(t01, gxA, t02)) + 1.0f) * 127.5f;
    const float uy2 = (fmaf(t00, gyA, fmaf(t01, gxB, t02)) + 1.0f) * 127.5f;
    const float uy3 = (fmaf(t00, gyB, fmaf(t01, gxA, t02)) + 1.0f) * 127.5f;
    const float uy4 = (fmaf(t00, gyB, fmaf(t01, gxB, t02)) + 1.0f) * 127.5f;
    const float ux1 = (fmaf(t10, gyA, fmaf(t11, gxA, t12)) + 1.0f) * 127.5f;
    const float ux2 = (fmaf(t10, gyA, fmaf(t11, gxB, t12)) + 1.0f) * 127.5f;
    const float ux3 = (fmaf(t10, gyB, fmaf(t11, gxA, t12)) + 1.0f) * 127.5f;
    const float ux4 = (fmaf(t10, gyB, fmaf(t11, gxB, t12)) + 1.0f) * 127.5f;
    const float uymin = fminf(fminf(uy1, uy2), fminf(uy3, uy4));
    const float uymax = fmaxf(fmaxf(uy1, uy2), fmaxf(uy3, uy4));
    const float uxmin = fminf(fminf(ux1, ux2), fminf(ux3, ux4));
    const float uxmax = fmaxf(fmaxf(ux1, ux2), fmaxf(ux3, ux4));
    const bool fits = (uymin > (float)row0 - 0.9f) && (uymax < (float)row0 + 7.9f) &&
                      (uxmin > (float)col0 - 1.9f) && (uxmax < (float)col0 + 32.9f);

    const int p  = tid >> 3;       // column within tile 0..31
    const int cg = tid & 7;        // float4 channel group
    const int wo = col0 + p;
    const float gx  = fmaf((float)wo, 2.0f / 255.0f, -1.0f);
    const float ayx = fmaf(t01, gx, t02);  // uy = t00*gy + ayx
    const float axx = fmaf(t11, gx, t12);  // ux = t10*gy + axx

    f32x4* op = (f32x4*)(out + (size_t)n * HW * CH);

    if (fits) {
        // ---- (4) unrolled blend from LDS ----
        const int iy_lo = row0 - 1, ix_lo = col0 - 2;
        #pragma unroll
        for (int k = 0; k < 8; ++k) {
            const int ho = row0 + k;
            const float gy = fmaf((float)ho, 2.0f / 255.0f, -1.0f);
            const float uy = (fmaf(t00, gy, ayx) + 1.0f) * 127.5f;
            const float ux = (fmaf(t10, gy, axx) + 1.0f) * 127.5f;
            const float fy = floorf(uy), fx = floorf(ux);
            const float ry = uy - fy, rx = ux - fx;
            const int iy0 = min(max((int)fy,     0), HDIM - 1);
            const int iy1 = min(max((int)fy + 1, 0), HDIM - 1);
            const int ix0 = min(max((int)fx,     0), WDIM - 1);
            const int ix1 = min(max((int)fx + 1, 0), WDIM - 1);
            const int ly0 = iy0 - iy_lo, ly1 = iy1 - iy_lo;
            const int lx0 = ix0 - ix_lo, lx1 = ix1 - ix_lo;
            float4 v00 = stage[(ly0 * C_CAP + lx0) * 8 + cg];
            float4 v01 = stage[(ly0 * C_CAP + lx1) * 8 + cg];
            float4 v10 = stage[(ly1 * C_CAP + lx0) * 8 + cg];
            float4 v11 = stage[(ly1 * C_CAP + lx1) * 8 + cg];
            const float w00 = (1.0f - ry) * (1.0f - rx);
            const float w01 = (1.0f - ry) * rx;
            const float w10 = ry * (1.0f - rx);
            const float w11 = ry * rx;
            f32x4 o;
            o.x = v00.x * w00 + v01.x * w01 + v10.x * w10 + v11.x * w11;
            o.y = v00.y * w00 + v01.y * w01 + v10.y * w10 + v11.y * w11;
            o.z = v00.z * w00 + v01.z * w01 + v10.z * w10 + v11.z * w11;
            o.w = v00.w * w00 + v01.w * w01 + v10.w * w10 + v11.w * w11;
            __builtin_nontemporal_store(o, &op[(size_t)(ho * WDIM + wo) * 8 + cg]);
        }
    } else {
        // ---- fallback: direct gather (correct for arbitrary theta) ----
        for (int k = 0; k < 8; ++k) {
            const int ho = row0 + k;
            const float gy = fmaf((float)ho, 2.0f / 255.0f, -1.0f);
            const float uy = (fmaf(t00, gy, ayx) + 1.0f) * 127.5f;
            const float ux = (fmaf(t10, gy, axx) + 1.0f) * 127.5f;
            const float fy = floorf(uy), fx = floorf(ux);
            const float ry = uy - fy, rx = ux - fx;
            const int iy0 = min(max((int)fy,     0), HDIM - 1);
            const int iy1 = min(max((int)fy + 1, 0), HDIM - 1);
            const int ix0 = min(max((int)fx,     0), WDIM - 1);
            const int ix1 = min(max((int)fx + 1, 0), WDIM - 1);
            float4 v00 = xp[(size_t)(iy0 * WDIM + ix0) * 8 + cg];
            float4 v01 = xp[(size_t)(iy0 * WDIM + ix1) * 8 + cg];
            float4 v10 = xp[(size_t)(iy1 * WDIM + ix0) * 8 + cg];
            float4 v11 = xp[(size_t)(iy1 * WDIM + ix1) * 8 + cg];
            const float w00 = (1.0f - ry) * (1.0f - rx);
            const float w01 = (1.0f - ry) * rx;
            const float w10 = ry * (1.0f - rx);
            const float w11 = ry * rx;
            f32x4 o;
            o.x = v00.x * w00 + v01.x * w01 + v10.x * w10 + v11.x * w11;
            o.y = v00.y * w00 + v01.y * w01 + v10.y * w10 + v11.y * w11;
            o.z = v00.z * w00 + v01.z * w01 + v10.z * w10 + v11.z * w11;
            o.w = v00.w * w00 + v01.w * w01 + v10.w * w10 + v11.w * w11;
            __builtin_nontemporal_store(o, &op[(size_t)(ho * WDIM + wo) * 8 + cg]);
        }
    }
}

extern "C" void kernel_launch(void* const* d_in, const int* in_sizes, int n_in,
                              void* d_out, int out_size, void* d_ws, size_t ws_size,
                              hipStream_t stream) {
    const float* x     = (const float*)d_in[0];
    const float* W_loc = (const float*)d_in[1];
    const float* b_loc = (const float*)d_in[2];
    float* out = (float*)d_out;

    float* partials = (float*)d_ws;  // [BPI][NIMG][CH]

    st_sum_kernel<<<NIMG * BPI, 256, 0, stream>>>(x, partials);
    st_interp_kernel<<<NIMG * (HW / 256), 256, 0, stream>>>(
        x, partials, W_loc, b_loc, out);
}

// Round 10
// 65.211 us; speedup vs baseline: 1.7925x; 1.0046x over previous
//
#include <hip/hip_runtime.h>

// Problem: SpatialTransform
//   x: (16,256,256,32) f32 -> out: (16,256,256,32) f32
//   theta = mean_pool(x) @ W_loc + b_loc;  out = bilinear_sample(x, affine_grid(theta))
//
// R9 lesson: three different read-path structures (direct gather MLP 8/16,
// DMA-staged LDS) all converge at interp ~39-41us -> read path not the limit.
// R10 A/B: drop nontemporal stores (every build since R2 had them; plain
// stores retire at L2, drain async) + halve the partials preamble (BPI 32).

#define NIMG 16
#define HDIM 256
#define WDIM 256
#define CH   32
#define HW   (HDIM * WDIM)
#define BPI  32    // sum-kernel blocks per image

typedef float f32x4 __attribute__((ext_vector_type(4)));

// ---------------------------------------------------------------------------
// Kernel 1: per-(n,c) partial sums. 512 blocks, 4 independent acc chains.
// partials layout: [BPI][NIMG][CH]
// ---------------------------------------------------------------------------
__global__ __launch_bounds__(256) void st_sum_kernel(
    const float* __restrict__ x, float* __restrict__ partials) {
    const int n   = blockIdx.x >> 5;
    const int blk = blockIdx.x & (BPI - 1);
    const int tid = threadIdx.x;
    const int cg  = tid & 7;    // float4 channel group
    const int sp  = tid >> 3;   // spatial slot 0..31

    const float4* xp = (const float4*)(x + (size_t)n * HW * CH);
    float4 a0 = make_float4(0.f, 0.f, 0.f, 0.f);
    float4 a1 = make_float4(0.f, 0.f, 0.f, 0.f);
    float4 a2 = make_float4(0.f, 0.f, 0.f, 0.f);
    float4 a3 = make_float4(0.f, 0.f, 0.f, 0.f);
    // 64 spatial iterations, 4 independent chains of 16. slot stride = 1024.
    int s = blk * 32 + sp;
    #pragma unroll
    for (int it = 0; it < 16; ++it) {
        float4 v0 = xp[(size_t)(s       ) * 8 + cg];
        float4 v1 = xp[(size_t)(s + 1024) * 8 + cg];
        float4 v2 = xp[(size_t)(s + 2048) * 8 + cg];
        float4 v3 = xp[(size_t)(s + 3072) * 8 + cg];
        a0.x += v0.x; a0.y += v0.y; a0.z += v0.z; a0.w += v0.w;
        a1.x += v1.x; a1.y += v1.y; a1.z += v1.z; a1.w += v1.w;
        a2.x += v2.x; a2.y += v2.y; a2.z += v2.z; a2.w += v2.w;
        a3.x += v3.x; a3.y += v3.y; a3.z += v3.z; a3.w += v3.w;
        s += 4096;
    }
    a0.x += a1.x; a0.y += a1.y; a0.z += a1.z; a0.w += a1.w;
    a2.x += a3.x; a2.y += a3.y; a2.z += a3.z; a2.w += a3.w;
    a0.x += a2.x; a0.y += a2.y; a0.z += a2.z; a0.w += a2.w;

    __shared__ float4 red[256];
    red[tid] = a0;
    __syncthreads();
    for (int stride = 16; stride >= 1; stride >>= 1) {
        if (sp < stride) {
            float4 o = red[(sp + stride) * 8 + cg];
            a0.x += o.x; a0.y += o.y; a0.z += o.z; a0.w += o.w;
            red[tid] = a0;
        }
        __syncthreads();
    }
    if (sp == 0) {
        ((float4*)(partials + ((size_t)blk * NIMG + n) * CH))[cg] = a0;
    }
}

// ---------------------------------------------------------------------------
// Kernel 2: per-block theta recompute + bilinear gather (R6 structure).
// One block = 4x32 pixel tile, 4 px per thread, 16 corner loads in flight.
// 8192 blocks; XCD swizzle gives each XCD 1024 consecutive blocks = 2 images.
// Plain stores (no NT): retire at L2, drain to HBM asynchronously.
// ---------------------------------------------------------------------------
__global__ __launch_bounds__(256) void st_interp_kernel(
    const float* __restrict__ x, const float* __restrict__ partials,
    const float* __restrict__ W_loc, const float* __restrict__ b_loc,
    float* __restrict__ out) {
    const int bid = (int)blockIdx.x;
    const int swz = (bid & 7) * 1024 + (bid >> 3);  // 8 XCDs contiguous
    const int n   = swz >> 9;                       // 512 blocks per image
    const int r   = swz & 511;
    const int tid = threadIdx.x;

    // ---- theta from partials (identical in every block of image n) ----
    __shared__ float red2[8][CH];
    __shared__ float th_s[8];
    {
        const int c = tid & 31, g = tid >> 5;  // g = 0..7
        float s = 0.f;
        #pragma unroll
        for (int j = 0; j < 4; ++j)
            s += partials[(size_t)((g * 4 + j) * NIMG + n) * CH + c];
        red2[g][c] = s;
        __syncthreads();
        if (g == 0) {
            float m = 0.f;
            #pragma unroll
            for (int j = 0; j < 8; ++j) m += red2[j][c];
            red2[0][c] = m * (1.0f / (float)HW);  // mean
        }
        __syncthreads();
        if (tid < 6) {
            float acc = b_loc[tid];
            for (int c2 = 0; c2 < CH; ++c2)
                acc = fmaf(red2[0][c2], W_loc[c2 * 6 + tid], acc);
            th_s[tid] = acc;
        }
        __syncthreads();
    }
    const float t00 = th_s[0], t01 = th_s[1], t02 = th_s[2];
    const float t10 = th_s[3], t11 = th_s[4], t12 = th_s[5];

    // ---- gather: 4x32 tile, 4 pixels per thread, 16 loads in flight ----
    const int ty = r >> 3;                         // 64 tile-rows (4 px each)
    const int tx = r & 7;                          // 8 tile-cols (32 px each)
    const int p  = tid >> 3;                       // pixel slot 0..31
    const int cg = tid & 7;                        // float4 channel group

    const int ho = ty * 4 + (p >> 3);
    const float gy = fmaf((float)ho, 2.0f / 255.0f, -1.0f);
    const float cy = fmaf(t00, gy, t02);           // uy before gx term
    const float cx = fmaf(t10, gy, t12);

    const float4* xp = (const float4*)(x + (size_t)n * HW * CH);

    int   off0[4], off1[4], off2[4], off3[4];
    float w00[4], w01[4], w10[4], w11[4];
    int   wo[4];
    #pragma unroll
    for (int k = 0; k < 4; ++k) {
        wo[k] = tx * 32 + (p & 7) + k * 8;
        const float gx = fmaf((float)wo[k], 2.0f / 255.0f, -1.0f);
        const float uy = (fmaf(t01, gx, cy) + 1.0f) * 127.5f;
        const float ux = (fmaf(t11, gx, cx) + 1.0f) * 127.5f;
        const float fy = floorf(uy), fx = floorf(ux);
        const float ry = uy - fy, rx = ux - fx;
        const int iy0 = min(max((int)fy,     0), HDIM - 1);
        const int iy1 = min(max((int)fy + 1, 0), HDIM - 1);
        const int ix0 = min(max((int)fx,     0), WDIM - 1);
        const int ix1 = min(max((int)fx + 1, 0), WDIM - 1);
        off0[k] = (iy0 * WDIM + ix0) * 8;
        off1[k] = (iy0 * WDIM + ix1) * 8;
        off2[k] = (iy1 * WDIM + ix0) * 8;
        off3[k] = (iy1 * WDIM + ix1) * 8;
        w00[k] = (1.0f - ry) * (1.0f - rx);
        w01[k] = (1.0f - ry) * rx;
        w10[k] = ry * (1.0f - rx);
        w11[k] = ry * rx;
    }

    // issue all 16 loads before any consumption
    float4 v00[4], v01[4], v10[4], v11[4];
    #pragma unroll
    for (int k = 0; k < 4; ++k) {
        v00[k] = xp[(size_t)off0[k] + cg];
        v01[k] = xp[(size_t)off1[k] + cg];
        v10[k] = xp[(size_t)off2[k] + cg];
        v11[k] = xp[(size_t)off3[k] + cg];
    }

    f32x4* op = (f32x4*)(out + (size_t)n * HW * CH);
    #pragma unroll
    for (int k = 0; k < 4; ++k) {
        f32x4 o;
        o.x = v00[k].x * w00[k] + v01[k].x * w01[k] + v10[k].x * w10[k] + v11[k].x * w11[k];
        o.y = v00[k].y * w00[k] + v01[k].y * w01[k] + v10[k].y * w10[k] + v11[k].y * w11[k];
        o.z = v00[k].z * w00[k] + v01[k].z * w01[k] + v10[k].z * w10[k] + v11[k].z * w11[k];
        o.w = v00[k].w * w00[k] + v01[k].w * w01[k] + v10[k].w * w10[k] + v11[k].w * w11[k];
        op[(size_t)(ho * WDIM + wo[k]) * 8 + cg] = o;   // plain store
    }
}

extern "C" void kernel_launch(void* const* d_in, const int* in_sizes, int n_in,
                              void* d_out, int out_size, void* d_ws, size_t ws_size,
                              hipStream_t stream) {
    const float* x     = (const float*)d_in[0];
    const float* W_loc = (const float*)d_in[1];
    const float* b_loc = (const float*)d_in[2];
    float* out = (float*)d_out;

    float* partials = (float*)d_ws;  // [BPI][NIMG][CH]

    st_sum_kernel<<<NIMG * BPI, 256, 0, stream>>>(x, partials);
    st_interp_kernel<<<NIMG * (HW / 128), 256, 0, stream>>>(
        x, partials, W_loc, b_loc, out);
}